// Round 1
// 189.469 us; speedup vs baseline: 1.0012x; 1.0012x over previous
//
#include <hip/hip_runtime.h>
#include <math.h>

#define KPOT 5
#define THREADS 256
#define RPT 4                                   // rows per thread (consecutive)
#define ROWS_PER_BLOCK (THREADS * RPT)          // 1024

typedef float v4f __attribute__((ext_vector_type(4)));

// Pure streaming design — no LDS, no barrier.
// Each thread owns 4 CONSECUTIVE rows:
//   x/noise/out: 2 float4 per thread (rows 4t..4t+3), 16B-aligned
//   gumbel:      5 float4 per thread (20 consecutive floats), 16B-aligned
// Every wave proceeds independently; compiler overlaps the logit FMAs
// (x-only) with the in-flight gumbel loads.
__global__ __launch_bounds__(THREADS) void lightsb_kernel(
    const float* __restrict__ x,
    const float* __restrict__ r,
    const float* __restrict__ log_S,
    const float* __restrict__ log_alpha,
    const float* __restrict__ gumbel,
    const float* __restrict__ noise,
    float* __restrict__ out,
    int n_rows)
{
    const int t = threadIdx.x;
    const long long blockRow0 = (long long)blockIdx.x * ROWS_PER_BLOCK;

    float S0[KPOT], S1[KPOT], r0[KPOT], r1[KPOT], la[KPOT];

    if (blockRow0 + ROWS_PER_BLOCK <= n_rows) {
        const float4* x4 = reinterpret_cast<const float4*>(x) + blockRow0 / 2;
        const float4* n4 = reinterpret_cast<const float4*>(noise) + blockRow0 / 2;
        const float4* g4 = reinterpret_cast<const float4*>(gumbel) + blockRow0 * KPOT / 4;

        // ---- issue all global loads up-front (9 x dwordx4, fully in registers) ----
        float4 xa = x4[2 * t];         // rows 4t, 4t+1
        float4 xb = x4[2 * t + 1];     // rows 4t+2, 4t+3
        float4 na = n4[2 * t];
        float4 nb = n4[2 * t + 1];

        float gf[RPT * KPOT];          // 20 consecutive gumbel floats, const-indexed
#pragma unroll
        for (int j = 0; j < KPOT; ++j) {
            float4 gv = g4[KPOT * t + j];
            gf[4 * j + 0] = gv.x;
            gf[4 * j + 1] = gv.y;
            gf[4 * j + 2] = gv.z;
            gf[4 * j + 3] = gv.w;
        }

        // ---- per-k constants (uniform, cached) while loads are in flight ----
#pragma unroll
        for (int k = 0; k < KPOT; ++k) {
            S0[k] = expf(log_S[2 * k + 0]);
            S1[k] = expf(log_S[2 * k + 1]);
            r0[k] = r[2 * k + 0];
            r1[k] = r[2 * k + 1];
            la[k] = log_alpha[k];
        }

        float ov[2 * RPT];

#pragma unroll
        for (int i = 0; i < RPT; ++i) {
            const float xx0 = (i == 0) ? xa.x : (i == 1) ? xa.z : (i == 2) ? xb.x : xb.z;
            const float xx1 = (i == 0) ? xa.y : (i == 1) ? xa.w : (i == 2) ? xb.y : xb.w;
            const float nn0 = (i == 0) ? na.x : (i == 1) ? na.z : (i == 2) ? nb.x : nb.z;
            const float nn1 = (i == 0) ? na.y : (i == 1) ? na.w : (i == 2) ? nb.y : nb.w;

            const float u0 = 0.5f * xx0 * xx0;
            const float u1 = 0.5f * xx1 * xx1;

            // logits_k = S0k*u0 + S1k*u1 + r0k*x0 + r1k*x1 + la_k + g_k
            float best = fmaf(S0[0], u0, fmaf(S1[0], u1,
                         fmaf(r0[0], xx0, fmaf(r1[0], xx1, la[0])))) + gf[KPOT * i + 0];
            float bS0 = S0[0], bS1 = S1[0];
            float br0 = r0[0], br1 = r1[0];
#pragma unroll
            for (int k = 1; k < KPOT; ++k) {
                float s = fmaf(S0[k], u0, fmaf(S1[k], u1,
                          fmaf(r0[k], xx0, fmaf(r1[k], xx1, la[k])))) + gf[KPOT * i + k];
                bool c = s > best;        // strict > keeps first max (jnp.argmax)
                best = c ? s : best;
                bS0 = c ? S0[k] : bS0;
                bS1 = c ? S1[k] : bS1;
                br0 = c ? r0[k] : br0;
                br1 = c ? r1[k] : br1;
            }
            const float bq0 = sqrtf(bS0);   // EPS = 1.0; sqrt only for selected k
            const float bq1 = sqrtf(bS1);
            ov[2 * i + 0] = fmaf(bS0, xx0, fmaf(bq0, nn0, br0));
            ov[2 * i + 1] = fmaf(bS1, xx1, fmaf(bq1, nn1, br1));
        }

        // ---- nontemporal stores: out is never re-read; don't evict inputs from L3 ----
        v4f* o4 = reinterpret_cast<v4f*>(out) + blockRow0 / 2;
        v4f o0 = { ov[0], ov[1], ov[2], ov[3] };
        v4f o1 = { ov[4], ov[5], ov[6], ov[7] };
        __builtin_nontemporal_store(o0, o4 + 2 * t);
        __builtin_nontemporal_store(o1, o4 + 2 * t + 1);
    } else {
        // ---- scalar fallback for a partial last block (n_rows % 1024 != 0) ----
        float q0[KPOT], q1[KPOT];
#pragma unroll
        for (int k = 0; k < KPOT; ++k) {
            float s0 = expf(log_S[2 * k + 0]);
            float s1 = expf(log_S[2 * k + 1]);
            S0[k] = s0;  S1[k] = s1;
            r0[k] = r[2 * k + 0];  r1[k] = r[2 * k + 1];
            la[k] = log_alpha[k];
            q0[k] = sqrtf(s0);  q1[k] = sqrtf(s1);
        }
        for (long long row = blockRow0 + t; row < n_rows; row += THREADS) {
            float x0 = x[row * 2 + 0];
            float x1 = x[row * 2 + 1];
            float u0 = 0.5f * x0 * x0;
            float u1 = 0.5f * x1 * x1;
            float best = fmaf(S0[0], u0, fmaf(S1[0], u1,
                         fmaf(r0[0], x0, fmaf(r1[0], x1, la[0] + gumbel[row * KPOT + 0])))); 
            int bidx = 0;
#pragma unroll
            for (int k = 1; k < KPOT; ++k) {
                float s = fmaf(S0[k], u0, fmaf(S1[k], u1,
                          fmaf(r0[k], x0, fmaf(r1[k], x1, la[k] + gumbel[row * KPOT + k]))));
                if (s > best) { best = s; bidx = k; }
            }
            float n0 = noise[row * 2 + 0];
            float n1 = noise[row * 2 + 1];
            out[row * 2 + 0] = fmaf(S0[bidx], x0, fmaf(q0[bidx], n0, r0[bidx]));
            out[row * 2 + 1] = fmaf(S1[bidx], x1, fmaf(q1[bidx], n1, r1[bidx]));
        }
    }
}

extern "C" void kernel_launch(void* const* d_in, const int* in_sizes, int n_in,
                              void* d_out, int out_size, void* d_ws, size_t ws_size,
                              hipStream_t stream) {
    const float* x         = (const float*)d_in[0];
    const float* r         = (const float*)d_in[1];
    const float* log_S     = (const float*)d_in[2];
    const float* log_alpha = (const float*)d_in[3];
    const float* gumbel    = (const float*)d_in[4];
    const float* noise     = (const float*)d_in[5];
    float* out = (float*)d_out;

    const int n_rows = in_sizes[0] / 2;                      // DIM = 2
    const int grid = (n_rows + ROWS_PER_BLOCK - 1) / ROWS_PER_BLOCK;

    lightsb_kernel<<<grid, THREADS, 0, stream>>>(x, r, log_S, log_alpha,
                                                 gumbel, noise, out, n_rows);
}